// Round 1
// baseline (369.886 us; speedup 1.0000x reference)
//
#include <hip/hip_runtime.h>

#define BB 2
#define AA 512
#define NN 1024
#define FF 64
#define DIN 128
#define DOUT 128
#define TH 25

typedef _Float16 half8 __attribute__((ext_vector_type(8)));
typedef float floatx4 __attribute__((ext_vector_type(4)));

__device__ __forceinline__ float ssp_f(float x) {
    // ln(0.5*e^x + 0.5) == softplus(x) - ln 2
    return __logf(0.5f * __expf(x) + 0.5f);
}

__device__ __forceinline__ float cutcos(float r) {
    float c = 0.5f * (__cosf(r * (3.14159265358979323846f / 5.0f)) + 1.0f);
    return (r < 5.0f) ? c : 0.0f;
}

// Kernel 1: y[ba][f] = sum_d x[ba][d] * W_in2f[d][f]
__global__ void in2f_kernel(const float* __restrict__ x,
                            const float* __restrict__ Wi,
                            float* __restrict__ y) {
    __shared__ float xs[DIN];
    const int ba = blockIdx.x;
    const int t = threadIdx.x;  // 64 threads
    xs[t] = x[ba * DIN + t];
    xs[t + 64] = x[ba * DIN + 64 + t];
    __syncthreads();
    float acc = 0.f;
#pragma unroll 8
    for (int d = 0; d < DIN; ++d) acc += xs[d] * Wi[d * FF + t];
    y[ba * FF + t] = acc;
}

// Kernel 2: fused triple-filter MLP + gather/interp + aggregation + f2out
__global__ __launch_bounds__(256) void triple_kernel(
    const float* __restrict__ r_ij, const float* __restrict__ r_ik,
    const int* __restrict__ nbrj, const int* __restrict__ nbrk,
    const float* __restrict__ tmask, const float* __restrict__ d_ijk,
    const float* __restrict__ W_t1, const float* __restrict__ b_t1,
    const float* __restrict__ W_t2, const float* __restrict__ b_t2,
    const float* __restrict__ W_f2out, const float* __restrict__ b_f2out,
    const float* __restrict__ y_tab, float* __restrict__ out) {

    // per-wave staging buffers (no cross-wave sharing -> no barriers in loop)
    __shared__ __align__(16) _Float16 a_tile[4][16][40];  // 16 rows x Kpad(32)+pad8
    __shared__ __align__(16) _Float16 h_tile[4][16][72];  // 16 rows x 64 + pad8
    __shared__ float row_wj[4][16];
    __shared__ float row_wk[4][16];
    __shared__ int   row_j[4][16];
    __shared__ int   row_k[4][16];
    __shared__ float red[4][FF];
    __shared__ float yag[FF];

    const int ba = blockIdx.x;
    const int b = ba >> 9;  // A = 512
    const int tid = threadIdx.x;
    const int w = tid >> 6;
    const int lane = tid & 63;
    const int quad = lane >> 4;
    const int l16 = lane & 15;

    const long ban = (long)ba * NN;
    const float* dbase = d_ijk + (long)ba * NN * TH;
    const int ybase = b * (AA * FF);

    // ---- preload weight fragments into registers ----
    // MFMA1 B operand: B[k][n], k = quad*8+j, n = g*16+l16  (K padded 25->32)
    half8 B1[4];
    half8 B2[4][2];
    float b1v[4], b2v[4];
#pragma unroll
    for (int g = 0; g < 4; ++g) {
#pragma unroll
        for (int j = 0; j < 8; ++j) {
            int k = quad * 8 + j;
            B1[g][j] = (k < TH) ? (_Float16)W_t1[k * FF + g * 16 + l16]
                                : (_Float16)0.f;
        }
        b1v[g] = b_t1[g * 16 + l16];
        b2v[g] = b_t2[g * 16 + l16];
#pragma unroll
        for (int q = 0; q < 2; ++q) {
#pragma unroll
            for (int j = 0; j < 8; ++j) {
                int k = q * 32 + quad * 8 + j;
                B2[g][q][j] = (_Float16)W_t2[k * FF + g * 16 + l16];
            }
        }
    }

    // zero the K-padding cols 25..31 of this wave's a_tile (once; never rewritten)
    for (int idx = lane; idx < 16 * 7; idx += 64) {
        int r = idx / 7, c = 25 + idx % 7;
        a_tile[w][r][c] = (_Float16)0.f;
    }

    floatx4 accy = {0.f, 0.f, 0.f, 0.f};
    const floatx4 zero4 = {0.f, 0.f, 0.f, 0.f};

    for (int tilei = w; tilei < NN / 16; tilei += 4) {
        const int n0 = tilei * 16;

        // ---- stage A: 16 rows x 25 floats, fully contiguous (400 floats) ----
        const float* dsrc = dbase + n0 * TH;
        for (int i = lane; i < 16 * TH; i += 64) {
            int r = i / TH, c = i - r * TH;
            a_tile[w][r][c] = (_Float16)dsrc[i];
        }
        // ---- stage per-row scalars (16 rows) ----
        if (lane < 16) {
            int n = n0 + lane;
            float rij = r_ij[ban + n];
            float rik = r_ik[ban + n];
            float msk = tmask[ban + n];
            float coef = cutcos(rij) * cutcos(rik) * msk;
            float inv = coef / (rij + rik);
            row_wj[w][lane] = rij * inv;  // coef * w_ij/(w_ij+w_ik)
            row_wk[w][lane] = rik * inv;
            row_j[w][lane] = ybase + nbrj[ban + n] * FF;
            row_k[w][lane] = ybase + nbrk[ban + n] * FF;
        }
        // same-wave LDS write->read: DS pipe is in-order per wave; no barrier.

        // ---- matmul1: h = ssp(d_tile @ W_t1 + b1)  (A: m=l16, k=quad*8+j) ----
        half8 afrag = *(const half8*)&a_tile[w][l16][quad * 8];
#pragma unroll
        for (int g = 0; g < 4; ++g) {
            floatx4 hv = __builtin_amdgcn_mfma_f32_16x16x32_f16(afrag, B1[g], zero4, 0, 0, 0);
#pragma unroll
            for (int r = 0; r < 4; ++r) {
                float v = ssp_f(hv[r] + b1v[g]);
                // C layout: row = quad*4+r, col = g*16+l16
                h_tile[w][quad * 4 + r][g * 16 + l16] = (_Float16)v;
            }
        }

        // ---- matmul2: w2 = h @ W_t2  (K = 64, two k-halves) ----
        half8 a2q0 = *(const half8*)&h_tile[w][l16][quad * 8];
        half8 a2q1 = *(const half8*)&h_tile[w][l16][32 + quad * 8];
        floatx4 w2[4];
#pragma unroll
        for (int g = 0; g < 4; ++g) {
            w2[g] = __builtin_amdgcn_mfma_f32_16x16x32_f16(a2q0, B2[g][0], zero4, 0, 0, 0);
            w2[g] = __builtin_amdgcn_mfma_f32_16x16x32_f16(a2q1, B2[g][1], w2[g], 0, 0, 0);
        }

        // ---- epilogue: gather + interpolate + accumulate ----
#pragma unroll
        for (int r = 0; r < 4; ++r) {
            int row = quad * 4 + r;
            float cwj = row_wj[w][row];
            float cwk = row_wk[w][row];
            const float* pj = y_tab + row_j[w][row] + l16;
            const float* pk = y_tab + row_k[w][row] + l16;
#pragma unroll
            for (int g = 0; g < 4; ++g) {
                float fv = cwj * pj[g * 16] + cwk * pk[g * 16];
                accy[g] += (w2[g][r] + b2v[g]) * fv;
            }
        }
    }

    // ---- reduce quads within wave (cols are per-l16) ----
#pragma unroll
    for (int g = 0; g < 4; ++g) {
        accy[g] += __shfl_xor(accy[g], 16, 64);
        accy[g] += __shfl_xor(accy[g], 32, 64);
    }
    if (quad == 0) {
#pragma unroll
        for (int g = 0; g < 4; ++g) red[w][g * 16 + l16] = accy[g];
    }
    __syncthreads();

    if (tid < FF) {
        yag[tid] = red[0][tid] + red[1][tid] + red[2][tid] + red[3][tid];
    }
    __syncthreads();

    // ---- f2out + ssp ----
    if (tid < DOUT) {
        float acc = b_f2out[tid];
#pragma unroll 8
        for (int f = 0; f < FF; ++f) acc += yag[f] * W_f2out[f * DOUT + tid];
        out[(long)ba * DOUT + tid] = ssp_f(acc);
    }
}

extern "C" void kernel_launch(void* const* d_in, const int* in_sizes, int n_in,
                              void* d_out, int out_size, void* d_ws, size_t ws_size,
                              hipStream_t stream) {
    const float* x       = (const float*)d_in[0];
    const float* r_ij    = (const float*)d_in[2];
    const float* r_ik    = (const float*)d_in[3];
    const int*   nbrj    = (const int*)d_in[7];
    const int*   nbrk    = (const int*)d_in[8];
    const float* tmask   = (const float*)d_in[9];
    const float* d_ijk   = (const float*)d_in[10];
    const float* W_in2f  = (const float*)d_in[11];
    const float* W_t1    = (const float*)d_in[12];
    const float* b_t1    = (const float*)d_in[13];
    const float* W_t2    = (const float*)d_in[14];
    const float* b_t2    = (const float*)d_in[15];
    const float* W_f2out = (const float*)d_in[16];
    const float* b_f2out = (const float*)d_in[17];
    float* out = (float*)d_out;
    float* y   = (float*)d_ws;  // B*A*F floats = 256 KB

    in2f_kernel<<<BB * AA, 64, 0, stream>>>(x, W_in2f, y);
    triple_kernel<<<BB * AA, 256, 0, stream>>>(r_ij, r_ik, nbrj, nbrk, tmask,
                                               d_ijk, W_t1, b_t1, W_t2, b_t2,
                                               W_f2out, b_f2out, y, out);
}

// Round 2
// 359.734 us; speedup vs baseline: 1.0282x; 1.0282x over previous
//
#include <hip/hip_runtime.h>

#define BB 2
#define AA 512
#define NN 1024
#define FF 64
#define DIN 128
#define DOUT 128
#define TH 25
#define ASTRIDE 40   // halves per a_tile row: 16B-aligned frag base, 2-way-free banks
#define HSTRIDE 72   // halves per h_tile row: 16B-aligned frag base, 2-way-free banks

typedef _Float16 half8 __attribute__((ext_vector_type(8)));
typedef float floatx4 __attribute__((ext_vector_type(4)));

__device__ __forceinline__ float ssp_f(float x) {
    return __logf(0.5f * __expf(x) + 0.5f);  // softplus(x) - ln2
}

__device__ __forceinline__ float cutcos(float r) {
    float c = 0.5f * (__cosf(r * (3.14159265358979323846f / 5.0f)) + 1.0f);
    return (r < 5.0f) ? c : 0.0f;
}

// Kernel 1: y[ba][f] = sum_d x[ba][d] * W_in2f[d][f], stored f16
__global__ void in2f_kernel(const float* __restrict__ x,
                            const float* __restrict__ Wi,
                            _Float16* __restrict__ y) {
    __shared__ float xs[DIN];
    const int ba = blockIdx.x;
    const int t = threadIdx.x;  // 64
    xs[t] = x[ba * DIN + t];
    xs[t + 64] = x[ba * DIN + 64 + t];
    __syncthreads();
    float acc = 0.f;
#pragma unroll 8
    for (int d = 0; d < DIN; ++d) acc += xs[d] * Wi[d * FF + t];
    y[ba * FF + t] = (_Float16)acc;
}

// Kernel 2: fused triple MLP + gather/interp + aggregation + f2out,
// software-pipelined: A-tile + row scalars prefetched in VGPRs, gathers
// issued before the MFMA chain and consumed after it.
__global__ __launch_bounds__(256, 4) void triple_kernel(
    const float* __restrict__ r_ij, const float* __restrict__ r_ik,
    const int* __restrict__ nbrj, const int* __restrict__ nbrk,
    const float* __restrict__ tmask, const float* __restrict__ d_ijk,
    const float* __restrict__ W_t1, const float* __restrict__ b_t1,
    const float* __restrict__ W_t2, const float* __restrict__ b_t2,
    const float* __restrict__ W_f2out, const float* __restrict__ b_f2out,
    const _Float16* __restrict__ y_tab, float* __restrict__ out) {

    // per-wave buffers -> no __syncthreads in main loop (same-wave DS is in-order)
    __shared__ __align__(16) _Float16 a_tile[4][16 * ASTRIDE];
    __shared__ __align__(16) _Float16 h_tile[4][16 * HSTRIDE];
    __shared__ float row_w[4][2][16];
    __shared__ int   row_i[4][2][16];
    __shared__ float red[4][FF];
    __shared__ float yag[FF];

    const int ba = blockIdx.x;
    const int b = ba >> 9;  // A = 512
    const int tid = threadIdx.x;
    const int w = tid >> 6;
    const int lane = tid & 63;
    const int quad = lane >> 4;
    const int l16 = lane & 15;

    const long ban = (long)ba * NN;
    const float* dbase = d_ijk + (long)ba * NN * TH;
    const _Float16* ybl = y_tab + (long)b * (AA * FF) + l16;

    // ---- weight fragments in registers ----
    half8 B1[4];
    half8 B2[4][2];
    float b1v[4], b2v[4];
#pragma unroll
    for (int g = 0; g < 4; ++g) {
#pragma unroll
        for (int j = 0; j < 8; ++j) {
            int k = quad * 8 + j;
            B1[g][j] = (k < TH) ? (_Float16)W_t1[k * FF + g * 16 + l16]
                                : (_Float16)0.f;
        }
        b1v[g] = b_t1[g * 16 + l16];
        b2v[g] = b_t2[g * 16 + l16];
#pragma unroll
        for (int q = 0; q < 2; ++q)
#pragma unroll
            for (int j = 0; j < 8; ++j)
                B2[g][q][j] = (_Float16)W_t2[(q * 32 + quad * 8 + j) * FF + g * 16 + l16];
    }

    // zero A-tile K-pad cols 25..31 once (never rewritten; avoids NaN garbage)
    for (int idx = lane; idx < 16 * 7; idx += 64) {
        int r = idx / 7, c = 25 + idx % 7;
        a_tile[w][r * ASTRIDE + c] = (_Float16)0.f;
    }

    // per-lane A staging map: slot s = m*64+lane of 400 contiguous floats
    int lofs[7];
    bool lval[7];
#pragma unroll
    for (int m = 0; m < 7; ++m) {
        int s = m * 64 + lane;
        lval[m] = (s < 400);
        int r = s / TH, c = s - r * TH;
        lofs[m] = lval[m] ? (r * ASTRIDE + c) : 0;
    }

    floatx4 accy = {0.f, 0.f, 0.f, 0.f};
    const floatx4 zero4 = {0.f, 0.f, 0.f, 0.f};

    // ---- prologue: prefetch tile(w) ----
    float pA[7];
    float s_rij = 0.f, s_rik = 0.f, s_msk = 0.f;
    int s_j = 0, s_k = 0;
    {
        const float* dsrc = dbase + w * 16 * TH;
#pragma unroll
        for (int m = 0; m < 7; ++m) pA[m] = lval[m] ? dsrc[m * 64 + lane] : 0.f;
        if (lane < 16) {
            int n = w * 16 + lane;
            s_rij = r_ij[ban + n];
            s_rik = r_ik[ban + n];
            s_msk = tmask[ban + n];
            s_j = nbrj[ban + n];
            s_k = nbrk[ban + n];
        }
    }

    for (int it = 0; it < NN / 64; ++it) {
        const int tile = w + it * 4;

        // 1. commit prefetched A regs -> LDS (f32 -> f16)
#pragma unroll
        for (int m = 0; m < 7; ++m)
            if (lval[m]) a_tile[w][lofs[m]] = (_Float16)pA[m];

        // 2. row scalars -> LDS
        if (lane < 16) {
            float coef = cutcos(s_rij) * cutcos(s_rik) * s_msk;
            float inv = coef / (s_rij + s_rik);
            row_w[w][0][lane] = s_rij * inv;
            row_w[w][1][lane] = s_rik * inv;
            row_i[w][0][lane] = s_j * FF;
            row_i[w][1][lane] = s_k * FF;
        }

        // 3. issue gathers for this tile (consumed after MFMA2)
        _Float16 gj[4][4], gk[4][4];
        float cwj[4], cwk[4];
#pragma unroll
        for (int r = 0; r < 4; ++r) {
            int row = quad * 4 + r;
            cwj[r] = row_w[w][0][row];
            cwk[r] = row_w[w][1][row];
            const _Float16* pj = ybl + row_i[w][0][row];
            const _Float16* pk = ybl + row_i[w][1][row];
#pragma unroll
            for (int g = 0; g < 4; ++g) {
                gj[r][g] = pj[g * 16];
                gk[r][g] = pk[g * 16];
            }
        }

        // 4. prefetch tile+4 (overlaps the whole MFMA/ssp chain below)
        if (it + 1 < NN / 64) {
            const float* dn = dbase + (tile + 4) * 16 * TH;
#pragma unroll
            for (int m = 0; m < 7; ++m)
                if (lval[m]) pA[m] = dn[m * 64 + lane];
            if (lane < 16) {
                int n = (tile + 4) * 16 + lane;
                s_rij = r_ij[ban + n];
                s_rik = r_ik[ban + n];
                s_msk = tmask[ban + n];
                s_j = nbrj[ban + n];
                s_k = nbrk[ban + n];
            }
        }

        // 5. matmul1 + ssp (A frag: m=l16, k=quad*8+j)
        half8 afrag = *(const half8*)&a_tile[w][l16 * ASTRIDE + quad * 8];
#pragma unroll
        for (int g = 0; g < 4; ++g) {
            floatx4 hv = __builtin_amdgcn_mfma_f32_16x16x32_f16(afrag, B1[g], zero4, 0, 0, 0);
#pragma unroll
            for (int r = 0; r < 4; ++r)
                h_tile[w][(quad * 4 + r) * HSTRIDE + g * 16 + l16] =
                    (_Float16)ssp_f(hv[r] + b1v[g]);
        }

        // 6. matmul2 (K=64)
        half8 a2q0 = *(const half8*)&h_tile[w][l16 * HSTRIDE + quad * 8];
        half8 a2q1 = *(const half8*)&h_tile[w][l16 * HSTRIDE + 32 + quad * 8];
        floatx4 w2[4];
#pragma unroll
        for (int g = 0; g < 4; ++g) {
            w2[g] = __builtin_amdgcn_mfma_f32_16x16x32_f16(a2q0, B2[g][0], zero4, 0, 0, 0);
            w2[g] = __builtin_amdgcn_mfma_f32_16x16x32_f16(a2q1, B2[g][1], w2[g], 0, 0, 0);
        }

        // 7. epilogue: interp + accumulate (gathers have had the chain to land)
#pragma unroll
        for (int r = 0; r < 4; ++r)
#pragma unroll
            for (int g = 0; g < 4; ++g) {
                float fv = cwj[r] * (float)gj[r][g] + cwk[r] * (float)gk[r][g];
                accy[g] += (w2[g][r] + b2v[g]) * fv;
            }
    }

    // ---- reduce quads within wave ----
#pragma unroll
    for (int g = 0; g < 4; ++g) {
        accy[g] += __shfl_xor(accy[g], 16, 64);
        accy[g] += __shfl_xor(accy[g], 32, 64);
    }
    if (quad == 0)
#pragma unroll
        for (int g = 0; g < 4; ++g) red[w][g * 16 + l16] = accy[g];
    __syncthreads();

    if (tid < FF)
        yag[tid] = red[0][tid] + red[1][tid] + red[2][tid] + red[3][tid];
    __syncthreads();

    // ---- f2out + ssp ----
    if (tid < DOUT) {
        float acc = b_f2out[tid];
#pragma unroll 8
        for (int f = 0; f < FF; ++f) acc += yag[f] * W_f2out[f * DOUT + tid];
        out[(long)ba * DOUT + tid] = ssp_f(acc);
    }
}

extern "C" void kernel_launch(void* const* d_in, const int* in_sizes, int n_in,
                              void* d_out, int out_size, void* d_ws, size_t ws_size,
                              hipStream_t stream) {
    const float* x       = (const float*)d_in[0];
    const float* r_ij    = (const float*)d_in[2];
    const float* r_ik    = (const float*)d_in[3];
    const int*   nbrj    = (const int*)d_in[7];
    const int*   nbrk    = (const int*)d_in[8];
    const float* tmask   = (const float*)d_in[9];
    const float* d_ijk   = (const float*)d_in[10];
    const float* W_in2f  = (const float*)d_in[11];
    const float* W_t1    = (const float*)d_in[12];
    const float* b_t1    = (const float*)d_in[13];
    const float* W_t2    = (const float*)d_in[14];
    const float* b_t2    = (const float*)d_in[15];
    const float* W_f2out = (const float*)d_in[16];
    const float* b_f2out = (const float*)d_in[17];
    float* out = (float*)d_out;
    _Float16* y = (_Float16*)d_ws;  // B*A*F halves = 128 KB

    in2f_kernel<<<BB * AA, 64, 0, stream>>>(x, W_in2f, y);
    triple_kernel<<<BB * AA, 256, 0, stream>>>(r_ij, r_ik, nbrj, nbrk, tmask,
                                               d_ijk, W_t1, b_t1, W_t2, b_t2,
                                               W_f2out, b_f2out, y, out);
}

// Round 3
// 301.868 us; speedup vs baseline: 1.2253x; 1.1917x over previous
//
#include <hip/hip_runtime.h>

#define BB 2
#define AA 512
#define NN 1024
#define FF 64
#define DIN 128
#define DOUT 128
#define TH 25
#define ASTRIDE 40   // halves per a_tile row (16B-aligned frag base)
#define HSTRIDE 72   // halves per h_tile / ft row (16B-aligned, 144B row pitch)

typedef _Float16 half8 __attribute__((ext_vector_type(8)));
typedef float floatx4 __attribute__((ext_vector_type(4)));

__device__ __forceinline__ float ssp_f(float x) {
    return __logf(0.5f * __expf(x) + 0.5f);  // softplus(x) - ln2
}

__device__ __forceinline__ float cutcos(float r) {
    float c = 0.5f * (__cosf(r * (3.14159265358979323846f / 5.0f)) + 1.0f);
    return (r < 5.0f) ? c : 0.0f;
}

// Kernel 1: y[ba][f] = sum_d x[ba][d] * W_in2f[d][f], stored f16 (one 128B line per row)
__global__ void in2f_kernel(const float* __restrict__ x,
                            const float* __restrict__ Wi,
                            _Float16* __restrict__ y) {
    __shared__ float xs[DIN];
    const int ba = blockIdx.x;
    const int t = threadIdx.x;  // 64
    xs[t] = x[ba * DIN + t];
    xs[t + 64] = x[ba * DIN + 64 + t];
    __syncthreads();
    float acc = 0.f;
#pragma unroll 8
    for (int d = 0; d < DIN; ++d) acc += xs[d] * Wi[d * FF + t];
    y[ba * FF + t] = (_Float16)acc;
}

// Kernel 2: fused triple MLP + vectorized gather/interp + aggregation + f2out
__global__ __launch_bounds__(256, 4) void triple_kernel(
    const float* __restrict__ r_ij, const float* __restrict__ r_ik,
    const int* __restrict__ nbrj, const int* __restrict__ nbrk,
    const float* __restrict__ tmask, const float* __restrict__ d_ijk,
    const float* __restrict__ W_t1, const float* __restrict__ b_t1,
    const float* __restrict__ W_t2, const float* __restrict__ b_t2,
    const float* __restrict__ W_f2out, const float* __restrict__ b_f2out,
    const _Float16* __restrict__ y_tab, float* __restrict__ out) {

    // per-wave buffers -> no __syncthreads in main loop (same-wave DS is in-order)
    __shared__ __align__(16) _Float16 a_tile[4][16 * ASTRIDE];
    __shared__ __align__(16) _Float16 h_tile[4][16 * HSTRIDE];
    __shared__ __align__(16) _Float16 ft[4][16 * HSTRIDE];   // filter transpose buf
    __shared__ float row_w[4][2][16];
    __shared__ int   row_i[4][2][16];
    __shared__ float red[4][FF];
    __shared__ float yag[FF];

    const int ba = blockIdx.x;
    const int b = ba >> 9;  // A = 512
    const int tid = threadIdx.x;
    const int w = tid >> 6;
    const int lane = tid & 63;
    const int quad = lane >> 4;
    const int l16 = lane & 15;
    const int rA = lane >> 3;        // row group 0..7 (rows rA and rA+8)
    const int fc = (lane & 7) * 8;   // feature chunk base (8 f16)

    const long ban = (long)ba * NN;
    const float* dbase = d_ijk + (long)ba * NN * TH;
    const _Float16* yb = y_tab + (long)b * (AA * FF);

    // ---- weight fragments in registers ----
    half8 B1[4];
    half8 B2[4][2];
    float b1v[4], b2v[4];
#pragma unroll
    for (int g = 0; g < 4; ++g) {
#pragma unroll
        for (int j = 0; j < 8; ++j) {
            int k = quad * 8 + j;
            B1[g][j] = (k < TH) ? (_Float16)W_t1[k * FF + g * 16 + l16]
                                : (_Float16)0.f;
        }
        b1v[g] = b_t1[g * 16 + l16];
        b2v[g] = b_t2[g * 16 + l16];
#pragma unroll
        for (int q = 0; q < 2; ++q)
#pragma unroll
            for (int j = 0; j < 8; ++j)
                B2[g][q][j] = (_Float16)W_t2[(q * 32 + quad * 8 + j) * FF + g * 16 + l16];
    }

    // zero A-tile K-pad cols 25..31 once
    for (int idx = lane; idx < 16 * 7; idx += 64) {
        int r = idx / 7, c = 25 + idx % 7;
        a_tile[w][r * ASTRIDE + c] = (_Float16)0.f;
    }

    // A staging map: 400 contiguous floats; 3 x float2/lane + 16-float tail
    int lofs2[3][2];
#pragma unroll
    for (int m = 0; m < 3; ++m)
#pragma unroll
        for (int e = 0; e < 2; ++e) {
            int s = m * 128 + lane * 2 + e;
            int r = s / TH, c = s - r * TH;
            lofs2[m][e] = r * ASTRIDE + c;
        }
    const int tofs = 15 * ASTRIDE + 9 + lane;  // tail: row 15, cols 9..24 (lane<16)

    float acc[8];
#pragma unroll
    for (int i = 0; i < 8; ++i) acc[i] = 0.f;
    const floatx4 zero4 = {0.f, 0.f, 0.f, 0.f};

    // ---- prologue: prefetch tile(w) ----
    float2 pA[3];
    float pT = 0.f;
    float s_rij = 0.f, s_rik = 0.f, s_msk = 0.f;
    int s_j = 0, s_k = 0;
    {
        const float* dsrc = dbase + w * 16 * TH;
#pragma unroll
        for (int m = 0; m < 3; ++m) pA[m] = *(const float2*)(dsrc + m * 128 + lane * 2);
        if (lane < 16) {
            pT = dsrc[384 + lane];
            int n = w * 16 + lane;
            s_rij = r_ij[ban + n];
            s_rik = r_ik[ban + n];
            s_msk = tmask[ban + n];
            s_j = nbrj[ban + n];
            s_k = nbrk[ban + n];
        }
    }

    for (int it = 0; it < NN / 64; ++it) {
        const int tile = w + it * 4;

        // 1. commit prefetched A -> LDS (f32 -> f16)
#pragma unroll
        for (int m = 0; m < 3; ++m) {
            a_tile[w][lofs2[m][0]] = (_Float16)pA[m].x;
            a_tile[w][lofs2[m][1]] = (_Float16)pA[m].y;
        }
        if (lane < 16) a_tile[w][tofs] = (_Float16)pT;

        // 2. row scalars -> LDS
        if (lane < 16) {
            float coef = cutcos(s_rij) * cutcos(s_rik) * s_msk;
            float inv = coef / (s_rij + s_rik);
            row_w[w][0][lane] = s_rij * inv;
            row_w[w][1][lane] = s_rik * inv;
            row_i[w][0][lane] = s_j * FF;
            row_i[w][1][lane] = s_k * FF;
        }

        // 3. issue vectorized gathers: rows rA and rA+8, 8 contiguous f16 each
        float wj0 = row_w[w][0][rA],     wk0 = row_w[w][1][rA];
        float wj1 = row_w[w][0][8 + rA], wk1 = row_w[w][1][8 + rA];
        half8 gj0 = *(const half8*)(yb + row_i[w][0][rA] + fc);
        half8 gj1 = *(const half8*)(yb + row_i[w][0][8 + rA] + fc);
        half8 gk0 = *(const half8*)(yb + row_i[w][1][rA] + fc);
        half8 gk1 = *(const half8*)(yb + row_i[w][1][8 + rA] + fc);

        // 4. prefetch tile+4 (overlaps MFMA/ssp chain)
        if (it + 1 < NN / 64) {
            const float* dn = dbase + (tile + 4) * 16 * TH;
#pragma unroll
            for (int m = 0; m < 3; ++m) pA[m] = *(const float2*)(dn + m * 128 + lane * 2);
            if (lane < 16) {
                pT = dn[384 + lane];
                int n = (tile + 4) * 16 + lane;
                s_rij = r_ij[ban + n];
                s_rik = r_ik[ban + n];
                s_msk = tmask[ban + n];
                s_j = nbrj[ban + n];
                s_k = nbrk[ban + n];
            }
        }

        // 5. matmul1 + ssp (A frag: m=l16, k=quad*8+j)
        half8 afrag = *(const half8*)&a_tile[w][l16 * ASTRIDE + quad * 8];
#pragma unroll
        for (int g = 0; g < 4; ++g) {
            floatx4 hv = __builtin_amdgcn_mfma_f32_16x16x32_f16(afrag, B1[g], zero4, 0, 0, 0);
#pragma unroll
            for (int r = 0; r < 4; ++r)
                h_tile[w][(quad * 4 + r) * HSTRIDE + g * 16 + l16] =
                    (_Float16)ssp_f(hv[r] + b1v[g]);
        }

        // 6. matmul2 (K=64) -> filter; transpose to gather layout via LDS
        half8 a2q0 = *(const half8*)&h_tile[w][l16 * HSTRIDE + quad * 8];
        half8 a2q1 = *(const half8*)&h_tile[w][l16 * HSTRIDE + 32 + quad * 8];
#pragma unroll
        for (int g = 0; g < 4; ++g) {
            floatx4 w2 = __builtin_amdgcn_mfma_f32_16x16x32_f16(a2q0, B2[g][0], zero4, 0, 0, 0);
            w2 = __builtin_amdgcn_mfma_f32_16x16x32_f16(a2q1, B2[g][1], w2, 0, 0, 0);
#pragma unroll
            for (int r = 0; r < 4; ++r)
                ft[w][(quad * 4 + r) * HSTRIDE + g * 16 + l16] =
                    (_Float16)(w2[r] + b2v[g]);
        }
        half8 f0 = *(const half8*)&ft[w][rA * HSTRIDE + fc];
        half8 f1 = *(const half8*)&ft[w][(8 + rA) * HSTRIDE + fc];

        // 7. epilogue: interp + accumulate (2 rows x 8 feats per lane)
#pragma unroll
        for (int i = 0; i < 8; ++i) {
            float fv0 = wj0 * (float)gj0[i] + wk0 * (float)gk0[i];
            float fv1 = wj1 * (float)gj1[i] + wk1 * (float)gk1[i];
            acc[i] += (float)f0[i] * fv0 + (float)f1[i] * fv1;
        }
    }

    // ---- reduce over row-groups (lane>>3) within wave ----
#pragma unroll
    for (int i = 0; i < 8; ++i) {
        acc[i] += __shfl_xor(acc[i], 8, 64);
        acc[i] += __shfl_xor(acc[i], 16, 64);
        acc[i] += __shfl_xor(acc[i], 32, 64);
    }
    if (lane < 8)
#pragma unroll
        for (int i = 0; i < 8; ++i) red[w][lane * 8 + i] = acc[i];
    __syncthreads();

    if (tid < FF)
        yag[tid] = red[0][tid] + red[1][tid] + red[2][tid] + red[3][tid];
    __syncthreads();

    // ---- f2out + ssp ----
    if (tid < DOUT) {
        float a = b_f2out[tid];
#pragma unroll 8
        for (int f = 0; f < FF; ++f) a += yag[f] * W_f2out[f * DOUT + tid];
        out[(long)ba * DOUT + tid] = ssp_f(a);
    }
}

extern "C" void kernel_launch(void* const* d_in, const int* in_sizes, int n_in,
                              void* d_out, int out_size, void* d_ws, size_t ws_size,
                              hipStream_t stream) {
    const float* x       = (const float*)d_in[0];
    const float* r_ij    = (const float*)d_in[2];
    const float* r_ik    = (const float*)d_in[3];
    const int*   nbrj    = (const int*)d_in[7];
    const int*   nbrk    = (const int*)d_in[8];
    const float* tmask   = (const float*)d_in[9];
    const float* d_ijk   = (const float*)d_in[10];
    const float* W_in2f  = (const float*)d_in[11];
    const float* W_t1    = (const float*)d_in[12];
    const float* b_t1    = (const float*)d_in[13];
    const float* W_t2    = (const float*)d_in[14];
    const float* b_t2    = (const float*)d_in[15];
    const float* W_f2out = (const float*)d_in[16];
    const float* b_f2out = (const float*)d_in[17];
    float* out = (float*)d_out;
    _Float16* y = (_Float16*)d_ws;  // B*A*F halves = 128 KB

    in2f_kernel<<<BB * AA, 64, 0, stream>>>(x, W_in2f, y);
    triple_kernel<<<BB * AA, 256, 0, stream>>>(r_ij, r_ik, nbrj, nbrk, tmask,
                                               d_ijk, W_t1, b_t1, W_t2, b_t2,
                                               W_f2out, b_f2out, y, out);
}